// Round 11
// baseline (324.055 us; speedup 1.0000x reference)
//
#include <hip/hip_runtime.h>
#include <hip/hip_bf16.h>
#include <math.h>

#define BB 16
#define IC 64
#define CH 128
#define LL 16384
#define KS 5
#define CAK 5
#define KCR 76
#define EPSV 1e-5f
#define NLT2 256          // psum/pmax partials per (b,c): 128 l-tiles x 2 half-waves
#define GROWS 8           // zero guard rows each side of the x_t scratch
#define XROWS (LL + 2 * GROWS)   // 16400 rows per batch in x_t

typedef short bf16x8 __attribute__((ext_vector_type(8)));
typedef float f32x16 __attribute__((ext_vector_type(16)));

// ---- workspace layout (in floats) ----
#define OFF_WPACK 0                          // 81920 ushort = 40960 floats (bf16 hi/lo A-frags)
#define OFF_BIAS2 40960                      // 128
#define OFF_PSUM  (OFF_BIAS2 + CH)           // 16*128*256
#define OFF_PMAX  (OFF_PSUM + BB*CH*NLT2)
#define OFF_CM    (OFF_PMAX + BB*CH*NLT2)    // 2048
#define OFF_MASK  (OFF_CM + BB*CH)
#define OFF_F16   (OFF_MASK + BB*CH)         // fp16 f: BB*CH*LL ushorts

__device__ __forceinline__ unsigned short f2bf(float f) {
    union { float f; unsigned u; } v; v.f = f;
    return (unsigned short)((v.u + 0x7FFFu + ((v.u >> 16) & 1u)) >> 16);
}
__device__ __forceinline__ float bf2f(unsigned short h) {
    union { unsigned u; float f; } v; v.u = ((unsigned)h) << 16;
    return v.f;
}
__device__ __forceinline__ unsigned short f2h(float f) {
    _Float16 h = (_Float16)f;
    return __builtin_bit_cast(unsigned short, h);
}
__device__ __forceinline__ float h2f(unsigned short u) {
    _Float16 h = __builtin_bit_cast(_Float16, u);
    return (float)h;
}

// async global -> LDS copy, 16B per lane (lds dest = uniform base + lane*16)
__device__ __forceinline__ void gload16(const void* g, void* l) {
    __builtin_amdgcn_global_load_lds(
        (const __attribute__((address_space(1))) void*)g,
        (__attribute__((address_space(3))) void*)l,
        16, 0, 0);
}

// DPP lane-shift (VALU pipe, no LDS). bound_ctrl=true: invalid lanes -> 0.
template<int CTRL>
__device__ __forceinline__ float dppf(float v) {
    return __builtin_bit_cast(float,
        __builtin_amdgcn_update_dpp(0, __builtin_bit_cast(int, v), CTRL, 0xF, 0xF, true));
}
__device__ __forceinline__ float dpp_sum32(float s) {
    s += dppf<0x111>(s);
    s += dppf<0x112>(s);
    s += dppf<0x114>(s);
    s += dppf<0x118>(s);
    s += dppf<0x142>(s);   // row_bcast:15 -> totals in lanes 31/63
    return s;
}
__device__ __forceinline__ float dpp_max32(float m) {
    m = fmaxf(m, dppf<0x111>(m));
    m = fmaxf(m, dppf<0x112>(m));
    m = fmaxf(m, dppf<0x114>(m));
    m = fmaxf(m, dppf<0x118>(m));
    m = fmaxf(m, dppf<0x142>(m));
    return m;
}

// ---------------------------------------------------------------------------
// Prep: fold BN scale into conv weights, split into bf16 hi/lo, pack in exact
// per-lane MFMA A-fragment order:
//   wpack[((((ver*2+ch2)*2+mt)*20+s)*64+ln)*8+j]
//     c = ch2*64 + mt*32 + (ln&31); kk = s>>2; i = (s&3)*16 + (ln>>5)*8 + j
// ---------------------------------------------------------------------------
__global__ void prep_kernel(const float* __restrict__ conv_w, const float* __restrict__ conv_b,
                            const float* __restrict__ bn_g, const float* __restrict__ bn_b,
                            const float* __restrict__ bn_m, const float* __restrict__ bn_v,
                            unsigned short* __restrict__ wpack, float* __restrict__ bias2)
{
    int e = blockIdx.x * 256 + threadIdx.x;
    if (e < 8 * 20 * 64 * 8) {
        int j    = e & 7;
        int ln   = (e >> 3) & 63;
        int rest = e >> 9;              // 0..159
        int s    = rest % 20;
        int mt   = (rest / 20) & 1;
        int ch2  = (rest / 40) & 1;
        int ver  = rest / 80;
        int c  = ch2 * 64 + mt * 32 + (ln & 31);
        int kk = s >> 2;
        int i  = (s & 3) * 16 + (ln >> 5) * 8 + j;
        float inv = bn_g[c] * rsqrtf(bn_v[c] + EPSV);
        float w = conv_w[(c * IC + i) * KS + kk] * inv;
        unsigned short h = f2bf(w);
        wpack[e] = (ver == 0) ? h : f2bf(w - bf2f(h));
    }
    if (e < CH) {
        float inv = bn_g[e] * rsqrtf(bn_v[e] + EPSV);
        bias2[e] = (conv_b[e] - bn_m[e]) * inv + bn_b[e];
    }
}

// ---------------------------------------------------------------------------
// Guard rows of x_t (8 rows of 256B, both ends, per batch) -> zeros.
// ---------------------------------------------------------------------------
__global__ void guard_kernel(unsigned short* __restrict__ xt)
{
    int b = blockIdx.x;
    int t = threadIdx.x;
    unsigned* p0 = (unsigned*)(xt + (size_t)b * XROWS * 128);
    unsigned* p1 = (unsigned*)(xt + ((size_t)b * XROWS + GROWS + LL) * 128);
    for (int k = t; k < GROWS * 64; k += 256) { p0[k] = 0; p1[k] = 0; }
}

// ---------------------------------------------------------------------------
// prex: convert x (fp32 [b][i][l]) -> x_t (bf16 hi|lo, [b][GROWS+l][row]),
// row = 256B: ushorts [chunk^((l+4)&7)]*8 + (i&7), hi in [0,64), lo at +64.
// This is exactly the conv kernel's LDS layout (pre-swizzled in global), so
// the conv can stage tiles with linear async global_load_lds copies.
// Block = (64 l) x (64 i), LDS transpose. Grid (256, B).
// ---------------------------------------------------------------------------
__global__ __launch_bounds__(256)
void prex_kernel(const float* __restrict__ x, unsigned short* __restrict__ xt)
{
    __shared__ float xtile[64][65];
    const int lg  = blockIdx.x;      // 0..255: 64-l group
    const int b   = blockIdx.y;
    const int tid = threadIdx.x;
    const int ln  = tid & 63;
    const int wv4 = tid >> 6;

    const float* xb = x + (size_t)b * IC * LL + (size_t)lg * 64;
    #pragma unroll
    for (int k = 0; k < 16; ++k) {
        int i = wv4 * 16 + k;
        xtile[i][ln] = xb[(size_t)i * LL + ln];
    }
    __syncthreads();

    unsigned* xtb = (unsigned*)(xt + ((size_t)b * XROWS + GROWS + (size_t)lg * 64) * 128);
    #pragma unroll
    for (int k = 0; k < 16; ++k) {
        int d  = tid + k * 256;          // 0..4095 linear dword over [64 rows][64 dwords]
        int r  = d >> 6;
        int dd = d & 63;
        int rs = ((lg * 64 + r) + 4) & 7;
        int s0 = (dd & 31) * 2;          // ushort slot within half-row
        int ch = (s0 >> 3) ^ rs;
        int i0 = (ch << 3) | (s0 & 7);
        float v0 = xtile[i0][r];
        float v1 = xtile[i0 + 1][r];
        unsigned short h0 = f2bf(v0), h1 = f2bf(v1);
        unsigned short u0, u1;
        if (dd < 32) { u0 = h0; u1 = h1; }
        else { u0 = f2bf(v0 - bf2f(h0)); u1 = f2bf(v1 - bf2f(h1)); }
        xtb[(size_t)r * 64 + dd] = (unsigned)u0 | ((unsigned)u1 << 16);
    }
}

// ---------------------------------------------------------------------------
// Split-bf16 MFMA conv + BN + ReLU -> f (fp16, ws) + per-channel partial
// sum/max (DPP). Block = 128c x 512l (4 tiles of 128l), 4 waves (64c x 64l).
// Double-buffered LDS; staging via async global_load_lds from the
// pre-swizzled x_t (34 exact 1KB chunks per tile, no VALU). Per tile:
// stage(t+1) issued first, then 20 K-slices x 12 MFMA (3-pass split merged),
// epilogue, one __syncthreads (drains vmcnt -> buf[t^1] ready).
// f = wh*xh + wh*xl + wl*xh  (fp32 MFMA accumulate; error ~4e-6 pre-f16).
// ---------------------------------------------------------------------------
__global__ __launch_bounds__(256, 2)
void conv_mfma_kernel(const unsigned short* __restrict__ xt,
                      const unsigned short* __restrict__ wpack,
                      const float* __restrict__ bias2,
                      unsigned short* __restrict__ f16,
                      float* __restrict__ psum, float* __restrict__ pmax)
{
    __shared__ unsigned short xs[2][136 * 128];   // 2 x 34,816 B
    const int b   = blockIdx.x;
    const int ltg = blockIdx.y;          // 0..31: group of 4 l-tiles
    const int tid = threadIdx.x;
    const int ln  = tid & 63;
    const int wv  = __builtin_amdgcn_readfirstlane(tid >> 6);

    const unsigned short* xtb = xt + (size_t)b * XROWS * 128;

    auto stage = [&](int buf, int tile) {
        // guarded row of l = tile*128 - 4 is (tile*128 - 4 + GROWS) = tile*128 + 4
        const char* src = (const char*)(xtb + ((size_t)tile * 128 + 4) * 128);
        char* dst = (char*)&xs[buf][0];
        #pragma unroll
        for (int g0 = 0; g0 < 9; ++g0) {
            int g = wv + g0 * 4;                   // 34 chunks of 1KB, round-robin
            if (g < 34)
                gload16(src + (size_t)g * 1024 + (size_t)ln * 16, dst + g * 1024);
        }
    };

    const int ch2  = wv >> 1;   // c-half
    const int lh   = wv & 1;    // l-half within a 128-l tile
    const int ln31 = ln & 31;
    const int hi   = ln >> 5;
    const int rowbase = lh * 64 + ln31 + 2;

    const unsigned short* wp  = wpack + (size_t)ln * 8;
    const unsigned short* pA0 = wp + (size_t)((ch2 * 2 + 0) * 20) * 512;       // wh, mt0
    const unsigned short* pA1 = wp + (size_t)((ch2 * 2 + 1) * 20) * 512;       // wh, mt1
    const unsigned short* pA2 = wp + (size_t)(((2 + ch2) * 2 + 0) * 20) * 512; // wl, mt0
    const unsigned short* pA3 = wp + (size_t)(((2 + ch2) * 2 + 1) * 20) * 512; // wl, mt1

    auto loadA = [&](bf16x8* Av, int s) {
        Av[0] = *(const bf16x8*)(pA0 + (size_t)s * 512);
        Av[1] = *(const bf16x8*)(pA1 + (size_t)s * 512);
        Av[2] = *(const bf16x8*)(pA2 + (size_t)s * 512);
        Av[3] = *(const bf16x8*)(pA3 + (size_t)s * 512);
    };
    auto loadB = [&](bf16x8* Bv, const unsigned short* bufp, int s) {
        int kk = s >> 2, iq = s & 3;
        int r0 = rowbase + kk;
        int r1 = r0 + 32;
        int c0 = ((iq << 1) + hi) ^ (r0 & 7);
        int c1 = ((iq << 1) + hi) ^ (r1 & 7);
        Bv[0] = *(const bf16x8*)&bufp[r0 * 128 + c0 * 8];        // bh, nt0
        Bv[1] = *(const bf16x8*)&bufp[r0 * 128 + 64 + c0 * 8];   // bl, nt0
        Bv[2] = *(const bf16x8*)&bufp[r1 * 128 + c1 * 8];        // bh, nt1
        Bv[3] = *(const bf16x8*)&bufp[r1 * 128 + 64 + c1 * 8];   // bl, nt1
    };

    f32x16 acc[2][2];
    auto compute = [&](const bf16x8* Av, const bf16x8* Bv) {
        acc[0][0] = __builtin_amdgcn_mfma_f32_32x32x16_bf16(Av[0], Bv[0], acc[0][0], 0, 0, 0);
        acc[1][0] = __builtin_amdgcn_mfma_f32_32x32x16_bf16(Av[1], Bv[0], acc[1][0], 0, 0, 0);
        acc[0][1] = __builtin_amdgcn_mfma_f32_32x32x16_bf16(Av[0], Bv[2], acc[0][1], 0, 0, 0);
        acc[1][1] = __builtin_amdgcn_mfma_f32_32x32x16_bf16(Av[1], Bv[2], acc[1][1], 0, 0, 0);
        acc[0][0] = __builtin_amdgcn_mfma_f32_32x32x16_bf16(Av[0], Bv[1], acc[0][0], 0, 0, 0);
        acc[1][0] = __builtin_amdgcn_mfma_f32_32x32x16_bf16(Av[1], Bv[1], acc[1][0], 0, 0, 0);
        acc[0][1] = __builtin_amdgcn_mfma_f32_32x32x16_bf16(Av[0], Bv[3], acc[0][1], 0, 0, 0);
        acc[1][1] = __builtin_amdgcn_mfma_f32_32x32x16_bf16(Av[1], Bv[3], acc[1][1], 0, 0, 0);
        acc[0][0] = __builtin_amdgcn_mfma_f32_32x32x16_bf16(Av[2], Bv[0], acc[0][0], 0, 0, 0);
        acc[1][0] = __builtin_amdgcn_mfma_f32_32x32x16_bf16(Av[3], Bv[0], acc[1][0], 0, 0, 0);
        acc[0][1] = __builtin_amdgcn_mfma_f32_32x32x16_bf16(Av[2], Bv[2], acc[0][1], 0, 0, 0);
        acc[1][1] = __builtin_amdgcn_mfma_f32_32x32x16_bf16(Av[3], Bv[2], acc[1][1], 0, 0, 0);
    };

    // ---- prologue: stage tile 0 ----
    stage(0, ltg * 4);
    __syncthreads();

    for (int t = 0; t < 4; ++t) {
        // issue async stage of next tile into the other buffer (no registers)
        if (t < 3) stage((t + 1) & 1, ltg * 4 + t + 1);

        const unsigned short* bufp = &xs[t & 1][0];
        #pragma unroll
        for (int mt = 0; mt < 2; ++mt)
            #pragma unroll
            for (int nt = 0; nt < 2; ++nt)
                #pragma unroll
                for (int r = 0; r < 16; ++r) acc[mt][nt][r] = 0.0f;

        bf16x8 Ar[3][4], Br[2][4];
        loadA(Ar[0], 0); loadA(Ar[1], 1); loadA(Ar[2], 2);
        loadB(Br[0], bufp, 0); loadB(Br[1], bufp, 1);
        #pragma unroll
        for (int s = 0; s < 20; ++s) {
            compute(Ar[s % 3], Br[s & 1]);
            if (s + 3 < 20) loadA(Ar[s % 3], s + 3);
            if (s + 2 < 20) loadB(Br[s & 1], bufp, s + 2);
        }

        // ---- epilogue: bias + relu, f16 store, per-channel partial sum/max ----
        // D mapping (32x32): col(l)=ln&31, row(c)=(r&3)+8*(r>>2)+4*(ln>>5)
        const int ltile  = ltg * 4 + t;
        const int lgbase = ltile * 128 + lh * 64 + ln31;
        #pragma unroll
        for (int mt = 0; mt < 2; ++mt) {
            #pragma unroll
            for (int nt = 0; nt < 2; ++nt) {
                #pragma unroll
                for (int r = 0; r < 16; ++r) {
                    int c = ch2 * 64 + mt * 32 + (r & 3) + 8 * (r >> 2) + 4 * hi;
                    float fv = fmaxf(acc[mt][nt][r] + bias2[c], 0.0f);
                    f16[((size_t)(b * CH + c)) * LL + lgbase + nt * 32] = f2h(fv);
                    acc[mt][nt][r] = fv;
                }
            }
        }
        #pragma unroll
        for (int mt = 0; mt < 2; ++mt) {
            #pragma unroll
            for (int r = 0; r < 16; ++r) {
                float s = dpp_sum32(acc[mt][0][r] + acc[mt][1][r]);
                float m = dpp_max32(fmaxf(acc[mt][0][r], acc[mt][1][r]));
                if (ln31 == 31) {
                    int c   = ch2 * 64 + mt * 32 + (r & 3) + 8 * (r >> 2) + 4 * hi;
                    int lt2 = ltile * 2 + lh;
                    psum[(b * CH + c) * NLT2 + lt2] = s;
                    pmax[(b * CH + c) * NLT2 + lt2] = m;
                }
            }
        }

        // drains vmcnt (stage of t+1 landed) + all waves done reading buf[t&1]
        __syncthreads();
    }
}

// ---------------------------------------------------------------------------
// Per-batch: finish L-reductions, channel attention, top-K mask (rank count,
// ties by lower index to match jax.lax.top_k). Grid: B x 128 threads.
// ---------------------------------------------------------------------------
__global__ void chan_kernel(const float* __restrict__ psum, const float* __restrict__ pmax,
                            const float* __restrict__ alpha, const float* __restrict__ beta,
                            const float* __restrict__ ca_w, const float* __restrict__ ca_b,
                            float* __restrict__ cm, float* __restrict__ maskv)
{
    int b = blockIdx.x;
    int c = threadIdx.x;   // 128
    const float* ps = psum + (b * CH + c) * NLT2;
    const float* pm = pmax + (b * CH + c) * NLT2;
    float s = 0.0f, m = 0.0f;
    for (int t = 0; t < NLT2; ++t) { s += ps[t]; m = fmaxf(m, pm[t]); }
    float favg = s * (1.0f / LL);
    float fadd = (alpha[0] + 0.5f) * favg + (beta[0] + 0.5f) * m;

    __shared__ float fa[CH];
    __shared__ float cms[CH];
    fa[c] = fadd;
    __syncthreads();

    float z = ca_b[0];
    #pragma unroll
    for (int k = 0; k < CAK; ++k) {
        int cc = c + k - 2;
        float v = (cc >= 0 && cc < CH) ? fa[cc] : 0.0f;
        z = fmaf(ca_w[k], v, z);
    }
    float cmv = 1.0f / (1.0f + expf(-z));
    cms[c] = cmv;
    __syncthreads();

    int rank = 0;
    for (int cc = 0; cc < CH; ++cc) {
        float o = cms[cc];
        rank += (o > cmv || (o == cmv && cc < c)) ? 1 : 0;
    }
    cm[b * CH + c] = cmv;
    maskv[b * CH + c] = (rank < KCR) ? 1.0f : 0.0f;
}

// ---------------------------------------------------------------------------
// Fused stats + gate + final, vectorized x2 along l.
// ---------------------------------------------------------------------------
__global__ __launch_bounds__(256)
void sgf_kernel(const unsigned short* __restrict__ f16, float* __restrict__ out,
                const float* __restrict__ cm, const float* __restrict__ maskv,
                const float* __restrict__ sa_w,
                const float* __restrict__ sabn_g, const float* __restrict__ sabn_b,
                const float* __restrict__ sabn_m, const float* __restrict__ sabn_v)
{
    __shared__ float cms[CH], mks[CH];
    __shared__ float st[4][520];
    const int g   = blockIdx.x;    // 0..31 (512-l tile)
    const int b   = blockIdx.y;
    const int l0  = g * 512;
    const int tid = threadIdx.x;
    if (tid < CH) { cms[tid] = cm[b * CH + tid]; mks[tid] = maskv[b * CH + tid]; }
    __syncthreads();

    {
        const unsigned short* fb = f16 + (size_t)b * CH * LL + l0 + 2 * tid;
        float cmx0 = 0.f, csm0 = 0.f, smx0 = 0.f, ssm0 = 0.f;
        float cmx1 = 0.f, csm1 = 0.f, smx1 = 0.f, ssm1 = 0.f;
        #pragma unroll 4
        for (int c = 0; c < CH; ++c) {
            unsigned pr = *(const unsigned*)(fb + (size_t)c * LL);
            float cmc = cms[c], mk = mks[c];
            float v0 = h2f((unsigned short)(pr & 0xFFFFu)) * cmc;
            float v1 = h2f((unsigned short)(pr >> 16)) * cmc;
            float vs0 = v0 * mk, vu0 = v0 - vs0;
            float vs1 = v1 * mk, vu1 = v1 - vs1;
            cmx0 = fmaxf(cmx0, vs0); smx0 = fmaxf(smx0, vu0); csm0 += vs0; ssm0 += vu0;
            cmx1 = fmaxf(cmx1, vs1); smx1 = fmaxf(smx1, vu1); csm1 += vs1; ssm1 += vu1;
        }
        int s0 = 3 + 2 * tid;
        st[0][s0] = cmx0;                  st[0][s0 + 1] = cmx1;
        st[1][s0] = csm0 * (1.0f / KCR);   st[1][s0 + 1] = csm1 * (1.0f / KCR);
        st[2][s0] = smx0;                  st[2][s0 + 1] = smx1;
        st[3][s0] = ssm0 * (1.0f / (CH - KCR));
        st[3][s0 + 1] = ssm1 * (1.0f / (CH - KCR));
    }
    if (tid < 6) {
        int slot = (tid < 3) ? tid : 515 + (tid - 3);
        int l = l0 - 3 + slot;
        float cmx = 0.f, csm = 0.f, smx = 0.f, ssm = 0.f;
        if (l >= 0 && l < LL) {
            const unsigned short* fb = f16 + (size_t)b * CH * LL + l;
            for (int c = 0; c < CH; ++c) {
                float v  = h2f(fb[(size_t)c * LL]) * cms[c];
                float mk = mks[c];
                float vs = v * mk, vu = v - vs;
                cmx = fmaxf(cmx, vs); smx = fmaxf(smx, vu);
                csm += vs; ssm += vu;
            }
        }
        st[0][slot] = cmx;
        st[1][slot] = csm * (1.0f / KCR);
        st[2][slot] = smx;
        st[3][slot] = ssm * (1.0f / (CH - KCR));
    }
    __syncthreads();

    float inv = sabn_g[0] * rsqrtf(sabn_v[0] + EPSV);
    float bb2 = sabn_b[0] - sabn_m[0] * inv;
    float y1a = 0.f, y2a = 0.f, y1b = 0.f, y2b = 0.f;
    #pragma unroll
    for (int k = 0; k < 7; ++k) {
        float wm = sa_w[k], wa = sa_w[7 + k];
        int s0 = 2 * tid + k;
        y1a = fmaf(wm, st[0][s0],     fmaf(wa, st[1][s0],     y1a));
        y2a = fmaf(wm, st[2][s0],     fmaf(wa, st[3][s0],     y2a));
        y1b = fmaf(wm, st[0][s0 + 1], fmaf(wa, st[1][s0 + 1], y1b));
        y2b = fmaf(wm, st[2][s0 + 1], fmaf(wa, st[3][s0 + 1], y2b));
    }
    float A1a = 1.0f / (1.0f + expf(-fmaxf(y1a * inv + bb2, 0.f)));
    float A2a = 1.0f / (1.0f + expf(-fmaxf(y2a * inv + bb2, 0.f)));
    float A1b = 1.0f / (1.0f + expf(-fmaxf(y1b * inv + bb2, 0.f)));
    float A2b = 1.0f / (1.0f + expf(-fmaxf(y2b * inv + bb2, 0.f)));

    const unsigned short* fb = f16 + (size_t)b * CH * LL + l0 + 2 * tid;
    float* ob = out + (size_t)b * CH * LL + l0 + 2 * tid;
    #pragma unroll 4
    for (int c = 0; c < CH; ++c) {
        unsigned pr = *(const unsigned*)(fb + (size_t)c * LL);
        float cmc = cms[c];
        float v0 = h2f((unsigned short)(pr & 0xFFFFu)) * cmc;
        float v1 = h2f((unsigned short)(pr >> 16)) * cmc;
        bool sel = (mks[c] > 0.5f);
        float2 w;
        w.x = v0 * (sel ? A1a : A2a);
        w.y = v1 * (sel ? A1b : A2b);
        *(float2*)(ob + (size_t)c * LL) = w;
    }
}

extern "C" void kernel_launch(void* const* d_in, const int* in_sizes, int n_in,
                              void* d_out, int out_size, void* d_ws, size_t ws_size,
                              hipStream_t stream)
{
    const float* x      = (const float*)d_in[0];
    const float* conv_w = (const float*)d_in[1];
    const float* conv_b = (const float*)d_in[2];
    const float* bn_g   = (const float*)d_in[3];
    const float* bn_b   = (const float*)d_in[4];
    const float* bn_m   = (const float*)d_in[5];
    const float* bn_v   = (const float*)d_in[6];
    const float* alpha  = (const float*)d_in[7];
    const float* beta   = (const float*)d_in[8];
    const float* ca_w   = (const float*)d_in[9];
    const float* ca_b   = (const float*)d_in[10];
    const float* sa_w   = (const float*)d_in[11];
    const float* sabn_g = (const float*)d_in[12];
    const float* sabn_b = (const float*)d_in[13];
    const float* sabn_m = (const float*)d_in[14];
    const float* sabn_v = (const float*)d_in[15];

    float* out = (float*)d_out;
    float* ws  = (float*)d_ws;

    unsigned short* wpack = (unsigned short*)(ws + OFF_WPACK);
    float* bias2 = ws + OFF_BIAS2;
    float* psum  = ws + OFF_PSUM;
    float* pmax  = ws + OFF_PMAX;
    float* cmv_  = ws + OFF_CM;
    float* mskv  = ws + OFF_MASK;
    unsigned short* f16p = (unsigned short*)(ws + OFF_F16);

    // x_t scratch lives in d_out (67.2 MB of 134 MB); sgf overwrites d_out last.
    unsigned short* xt = (unsigned short*)d_out;

    prep_kernel<<<320, 256, 0, stream>>>(conv_w, conv_b, bn_g, bn_b, bn_m, bn_v,
                                         wpack, bias2);

    guard_kernel<<<BB, 256, 0, stream>>>(xt);

    prex_kernel<<<dim3(256, BB), 256, 0, stream>>>(x, xt);

    conv_mfma_kernel<<<dim3(BB, 32), 256, 0, stream>>>(xt, wpack, bias2, f16p, psum, pmax);

    chan_kernel<<<BB, CH, 0, stream>>>(psum, pmax, alpha, beta, ca_w, ca_b, cmv_, mskv);

    sgf_kernel<<<dim3(32, BB), 256, 0, stream>>>(f16p, out, cmv_, mskv, sa_w,
                                                 sabn_g, sabn_b, sabn_m, sabn_v);
}

// Round 12
// 159.691 us; speedup vs baseline: 2.0293x; 2.0293x over previous
//
#include <hip/hip_runtime.h>
#include <hip/hip_bf16.h>
#include <math.h>

#define BB 16
#define IC 64
#define CH 128
#define LL 16384
#define KS 5
#define CAK 5
#define KCR 76
#define EPSV 1e-5f
#define NLT2 256          // psum/pmax partials per (b,c): 128 l-tiles x 2 half-waves

typedef short bf16x8 __attribute__((ext_vector_type(8)));
typedef float f32x16 __attribute__((ext_vector_type(16)));

// ---- workspace layout (in floats) ----
#define OFF_WPACK 0                          // 81920 ushort = 40960 floats (bf16 hi/lo A-frags)
#define OFF_BIAS2 40960                      // 128
#define OFF_PSUM  (OFF_BIAS2 + CH)           // 16*128*256
#define OFF_PMAX  (OFF_PSUM + BB*CH*NLT2)
#define OFF_CM    (OFF_PMAX + BB*CH*NLT2)    // 2048
#define OFF_MASK  (OFF_CM + BB*CH)
#define OFF_F16   (OFF_MASK + BB*CH)         // fp16 f: BB*CH*LL ushorts

__device__ __forceinline__ unsigned short f2bf(float f) {
    union { float f; unsigned u; } v; v.f = f;
    return (unsigned short)((v.u + 0x7FFFu + ((v.u >> 16) & 1u)) >> 16);
}
__device__ __forceinline__ float bf2f(unsigned short h) {
    union { unsigned u; float f; } v; v.u = ((unsigned)h) << 16;
    return v.f;
}
__device__ __forceinline__ unsigned short f2h(float f) {
    _Float16 h = (_Float16)f;
    return __builtin_bit_cast(unsigned short, h);
}
__device__ __forceinline__ float h2f(unsigned short u) {
    _Float16 h = __builtin_bit_cast(_Float16, u);
    return (float)h;
}

// DPP lane-shift (VALU pipe, no LDS). bound_ctrl=true: invalid lanes -> 0.
template<int CTRL>
__device__ __forceinline__ float dppf(float v) {
    return __builtin_bit_cast(float,
        __builtin_amdgcn_update_dpp(0, __builtin_bit_cast(int, v), CTRL, 0xF, 0xF, true));
}
__device__ __forceinline__ float dpp_sum32(float s) {
    s += dppf<0x111>(s);
    s += dppf<0x112>(s);
    s += dppf<0x114>(s);
    s += dppf<0x118>(s);
    s += dppf<0x142>(s);   // row_bcast:15 -> totals in lanes 31/63
    return s;
}
__device__ __forceinline__ float dpp_max32(float m) {
    m = fmaxf(m, dppf<0x111>(m));
    m = fmaxf(m, dppf<0x112>(m));
    m = fmaxf(m, dppf<0x114>(m));
    m = fmaxf(m, dppf<0x118>(m));
    m = fmaxf(m, dppf<0x142>(m));
    return m;
}

// ---------------------------------------------------------------------------
// Prep: fold BN scale into conv weights, split into bf16 hi/lo, pack in exact
// per-lane MFMA A-fragment order:
//   wpack[((((ver*2+ch2)*2+mt)*20+s)*64+ln)*8+j]
//     c = ch2*64 + mt*32 + (ln&31); kk = s>>2; i = (s&3)*16 + (ln>>5)*8 + j
// ---------------------------------------------------------------------------
__global__ void prep_kernel(const float* __restrict__ conv_w, const float* __restrict__ conv_b,
                            const float* __restrict__ bn_g, const float* __restrict__ bn_b,
                            const float* __restrict__ bn_m, const float* __restrict__ bn_v,
                            unsigned short* __restrict__ wpack, float* __restrict__ bias2)
{
    int e = blockIdx.x * 256 + threadIdx.x;
    if (e < 8 * 20 * 64 * 8) {
        int j    = e & 7;
        int ln   = (e >> 3) & 63;
        int rest = e >> 9;              // 0..159
        int s    = rest % 20;
        int mt   = (rest / 20) & 1;
        int ch2  = (rest / 40) & 1;
        int ver  = rest / 80;
        int c  = ch2 * 64 + mt * 32 + (ln & 31);
        int kk = s >> 2;
        int i  = (s & 3) * 16 + (ln >> 5) * 8 + j;
        float inv = bn_g[c] * rsqrtf(bn_v[c] + EPSV);
        float w = conv_w[(c * IC + i) * KS + kk] * inv;
        unsigned short h = f2bf(w);
        wpack[e] = (ver == 0) ? h : f2bf(w - bf2f(h));
    }
    if (e < CH) {
        float inv = bn_g[e] * rsqrtf(bn_v[e] + EPSV);
        bias2[e] = (conv_b[e] - bn_m[e]) * inv + bn_b[e];
    }
}

// ---------------------------------------------------------------------------
// Split-bf16 MFMA conv + BN + ReLU -> f (fp16, ws) + per-channel partial
// sum/max (DPP, fp32 pre-quant). Block = 128c x 128l, 4 waves of (64c x 64l).
// LDS tile xs[136][128] = [64 hi bf16 | 64 lo bf16], 16B chunks XOR-swizzled
// by (row&7). f = wh*xh + wh*xl + wl*xh  (fp32 MFMA accumulate, err ~4e-6).
// ---------------------------------------------------------------------------
__global__ __launch_bounds__(256, 4)
void conv_mfma_kernel(const float* __restrict__ x,
                      const unsigned short* __restrict__ wpack,
                      const float* __restrict__ bias2,
                      unsigned short* __restrict__ f16,
                      float* __restrict__ psum, float* __restrict__ pmax)
{
    __shared__ unsigned short xs[136 * 128];   // 34,816 B -> 4 blocks/CU
    const int b   = blockIdx.x;
    const int lt  = blockIdx.y;
    const int l0  = lt * 128;
    const int tid = threadIdx.x;
    const int ln  = tid & 63;
    const int wv  = __builtin_amdgcn_readfirstlane(tid >> 6);

    // ---- staging: wave wv owns i in [wv*16, wv*16+16); lane = row (l) ----
    const float* xb = x + (size_t)b * (IC * LL);
    const int ibase = wv * 16;
    #pragma unroll
    for (int g = 0; g < 3; ++g) {
        int row = g * 64 + ln;           // 0..191; valid rows < 136
        int l   = l0 - 4 + row;
        if (row < 136) {
            bool vl = (l >= 0) && (l < LL);
            float v[16];
            #pragma unroll
            for (int q = 0; q < 16; ++q)
                v[q] = vl ? xb[(size_t)(ibase + q) * LL + l] : 0.0f;
            int rs = row & 7;
            #pragma unroll
            for (int q2 = 0; q2 < 4; ++q2) {
                unsigned short h[4], lo[4];
                #pragma unroll
                for (int j = 0; j < 4; ++j) {
                    float vv = v[q2 * 4 + j];
                    h[j]  = f2bf(vv);
                    lo[j] = f2bf(vv - bf2f(h[j]));
                }
                int i0   = ibase + q2 * 4;
                int cc   = (i0 >> 3) ^ rs;
                int epos = row * 128 + cc * 8 + (i0 & 7);
                uint2 wh, wl;
                wh.x = (unsigned)h[0]  | ((unsigned)h[1]  << 16);
                wh.y = (unsigned)h[2]  | ((unsigned)h[3]  << 16);
                wl.x = (unsigned)lo[0] | ((unsigned)lo[1] << 16);
                wl.y = (unsigned)lo[2] | ((unsigned)lo[3] << 16);
                *(uint2*)&xs[epos]      = wh;
                *(uint2*)&xs[epos + 64] = wl;
            }
        }
    }
    __syncthreads();

    const int ch2  = wv >> 1;   // c-half: 0 -> c 0..63, 1 -> 64..127
    const int lh   = wv & 1;    // l-half within the 128-l tile
    const int ln31 = ln & 31;
    const int hi   = ln >> 5;
    const int rowbase = lh * 64 + ln31 + 2;

    // A-fragment stream pointers (wpack is L2-hot, 160 KB)
    const unsigned short* wp  = wpack + (size_t)ln * 8;
    const unsigned short* pA0 = wp + (size_t)((ch2 * 2 + 0) * 20) * 512;       // wh, mt0
    const unsigned short* pA1 = wp + (size_t)((ch2 * 2 + 1) * 20) * 512;       // wh, mt1
    const unsigned short* pA2 = wp + (size_t)(((2 + ch2) * 2 + 0) * 20) * 512; // wl, mt0
    const unsigned short* pA3 = wp + (size_t)(((2 + ch2) * 2 + 1) * 20) * 512; // wl, mt1

    f32x16 acc[2][2];
    #pragma unroll
    for (int mt = 0; mt < 2; ++mt)
        #pragma unroll
        for (int nt = 0; nt < 2; ++nt)
            #pragma unroll
            for (int r = 0; r < 16; ++r) acc[mt][nt][r] = 0.0f;

    auto loadA = [&](bf16x8* Av, int s) {
        Av[0] = *(const bf16x8*)(pA0 + (size_t)s * 512);
        Av[1] = *(const bf16x8*)(pA1 + (size_t)s * 512);
        Av[2] = *(const bf16x8*)(pA2 + (size_t)s * 512);
        Av[3] = *(const bf16x8*)(pA3 + (size_t)s * 512);
    };
    auto loadB = [&](bf16x8* Bv, int s) {
        int kk = s >> 2, iq = s & 3;
        int r0 = rowbase + kk;
        int r1 = r0 + 32;
        int c0 = ((iq << 1) + hi) ^ (r0 & 7);
        int c1 = ((iq << 1) + hi) ^ (r1 & 7);
        Bv[0] = *(const bf16x8*)&xs[r0 * 128 + c0 * 8];        // bh, nt0
        Bv[1] = *(const bf16x8*)&xs[r0 * 128 + 64 + c0 * 8];   // bl, nt0
        Bv[2] = *(const bf16x8*)&xs[r1 * 128 + c1 * 8];        // bh, nt1
        Bv[3] = *(const bf16x8*)&xs[r1 * 128 + 64 + c1 * 8];   // bl, nt1
    };
    // Interleaved across the 4 accumulators: same-acc dep distance = 4.
    auto compute = [&](const bf16x8* Av, const bf16x8* Bv) {
        acc[0][0] = __builtin_amdgcn_mfma_f32_32x32x16_bf16(Av[0], Bv[0], acc[0][0], 0, 0, 0);
        acc[1][0] = __builtin_amdgcn_mfma_f32_32x32x16_bf16(Av[1], Bv[0], acc[1][0], 0, 0, 0);
        acc[0][1] = __builtin_amdgcn_mfma_f32_32x32x16_bf16(Av[0], Bv[2], acc[0][1], 0, 0, 0);
        acc[1][1] = __builtin_amdgcn_mfma_f32_32x32x16_bf16(Av[1], Bv[2], acc[1][1], 0, 0, 0);
        acc[0][0] = __builtin_amdgcn_mfma_f32_32x32x16_bf16(Av[0], Bv[1], acc[0][0], 0, 0, 0);
        acc[1][0] = __builtin_amdgcn_mfma_f32_32x32x16_bf16(Av[1], Bv[1], acc[1][0], 0, 0, 0);
        acc[0][1] = __builtin_amdgcn_mfma_f32_32x32x16_bf16(Av[0], Bv[3], acc[0][1], 0, 0, 0);
        acc[1][1] = __builtin_amdgcn_mfma_f32_32x32x16_bf16(Av[1], Bv[3], acc[1][1], 0, 0, 0);
        acc[0][0] = __builtin_amdgcn_mfma_f32_32x32x16_bf16(Av[2], Bv[0], acc[0][0], 0, 0, 0);
        acc[1][0] = __builtin_amdgcn_mfma_f32_32x32x16_bf16(Av[3], Bv[0], acc[1][0], 0, 0, 0);
        acc[0][1] = __builtin_amdgcn_mfma_f32_32x32x16_bf16(Av[2], Bv[2], acc[0][1], 0, 0, 0);
        acc[1][1] = __builtin_amdgcn_mfma_f32_32x32x16_bf16(Av[3], Bv[2], acc[1][1], 0, 0, 0);
    };

    // ---- main loop: 3-deep A ring, 2-deep B ring ----
    bf16x8 Ar[3][4], Br[2][4];
    loadA(Ar[0], 0); loadA(Ar[1], 1); loadA(Ar[2], 2);
    loadB(Br[0], 0); loadB(Br[1], 1);
    #pragma unroll
    for (int s = 0; s < 20; ++s) {
        compute(Ar[s % 3], Br[s & 1]);
        if (s + 3 < 20) loadA(Ar[s % 3], s + 3);
        if (s + 2 < 20) loadB(Br[s & 1], s + 2);
    }

    // ---- epilogue: bias + relu, store f16, per-channel partial sum/max ----
    // D mapping (32x32): col(l)=ln&31, row(c)=(r&3)+8*(r>>2)+4*(ln>>5)
    const int lgbase = l0 + lh * 64 + ln31;
    #pragma unroll
    for (int mt = 0; mt < 2; ++mt) {
        #pragma unroll
        for (int nt = 0; nt < 2; ++nt) {
            #pragma unroll
            for (int r = 0; r < 16; ++r) {
                int c = ch2 * 64 + mt * 32 + (r & 3) + 8 * (r >> 2) + 4 * hi;
                float fv = fmaxf(acc[mt][nt][r] + bias2[c], 0.0f);
                f16[((size_t)(b * CH + c)) * LL + lgbase + nt * 32] = f2h(fv);
                acc[mt][nt][r] = fv;
            }
        }
    }
    // per-channel partial sum/max over this wave's 64 l's, via DPP (no LDS).
    #pragma unroll
    for (int mt = 0; mt < 2; ++mt) {
        #pragma unroll
        for (int r = 0; r < 16; ++r) {
            float s = dpp_sum32(acc[mt][0][r] + acc[mt][1][r]);
            float m = dpp_max32(fmaxf(acc[mt][0][r], acc[mt][1][r]));
            if (ln31 == 31) {
                int c   = ch2 * 64 + mt * 32 + (r & 3) + 8 * (r >> 2) + 4 * hi;
                int lt2 = lt * 2 + lh;
                psum[(b * CH + c) * NLT2 + lt2] = s;
                pmax[(b * CH + c) * NLT2 + lt2] = m;
            }
        }
    }
}

// ---------------------------------------------------------------------------
// Per-batch: finish L-reductions (float4-vectorized), channel attention,
// top-K mask (rank count, ties by lower index = jax.lax.top_k). Grid: B x 128.
// ---------------------------------------------------------------------------
__global__ void chan_kernel(const float* __restrict__ psum, const float* __restrict__ pmax,
                            const float* __restrict__ alpha, const float* __restrict__ beta,
                            const float* __restrict__ ca_w, const float* __restrict__ ca_b,
                            float* __restrict__ cm, float* __restrict__ maskv)
{
    int b = blockIdx.x;
    int c = threadIdx.x;   // 128
    const float4* ps4 = (const float4*)(psum + (size_t)(b * CH + c) * NLT2);
    const float4* pm4 = (const float4*)(pmax + (size_t)(b * CH + c) * NLT2);
    float s = 0.0f, m = 0.0f;
    #pragma unroll 4
    for (int t = 0; t < NLT2 / 4; ++t) {
        float4 a = ps4[t];
        float4 q = pm4[t];
        s += (a.x + a.y) + (a.z + a.w);
        m = fmaxf(m, fmaxf(fmaxf(q.x, q.y), fmaxf(q.z, q.w)));
    }
    float favg = s * (1.0f / LL);
    float fadd = (alpha[0] + 0.5f) * favg + (beta[0] + 0.5f) * m;

    __shared__ float fa[CH];
    __shared__ float cms[CH];
    fa[c] = fadd;
    __syncthreads();

    float z = ca_b[0];
    #pragma unroll
    for (int k = 0; k < CAK; ++k) {
        int cc = c + k - 2;
        float v = (cc >= 0 && cc < CH) ? fa[cc] : 0.0f;
        z = fmaf(ca_w[k], v, z);
    }
    float cmv = 1.0f / (1.0f + expf(-z));
    cms[c] = cmv;
    __syncthreads();

    int rank = 0;
    for (int cc = 0; cc < CH; ++cc) {
        float o = cms[cc];
        rank += (o > cmv || (o == cmv && cc < c)) ? 1 : 0;
    }
    cm[b * CH + c] = cmv;
    maskv[b * CH + c] = (rank < KCR) ? 1.0f : 0.0f;
}

// ---------------------------------------------------------------------------
// Fused stats + gate + final, vectorized x2 along l. Halo stat slots computed
// by 6 x 32-lane groups (was 6 lone threads) -> no serial 128-iter tail.
// ---------------------------------------------------------------------------
__global__ __launch_bounds__(256)
void sgf_kernel(const unsigned short* __restrict__ f16, float* __restrict__ out,
                const float* __restrict__ cm, const float* __restrict__ maskv,
                const float* __restrict__ sa_w,
                const float* __restrict__ sabn_g, const float* __restrict__ sabn_b,
                const float* __restrict__ sabn_m, const float* __restrict__ sabn_v)
{
    __shared__ float cms[CH], mks[CH];
    __shared__ float st[4][520];
    const int g   = blockIdx.x;    // 0..31 (512-l tile)
    const int b   = blockIdx.y;
    const int l0  = g * 512;
    const int tid = threadIdx.x;
    if (tid < CH) { cms[tid] = cm[b * CH + tid]; mks[tid] = maskv[b * CH + tid]; }
    __syncthreads();

    // ---- interior stats: 2 adjacent l per thread, uint loads ----
    {
        const unsigned short* fb = f16 + (size_t)b * CH * LL + l0 + 2 * tid;
        float cmx0 = 0.f, csm0 = 0.f, smx0 = 0.f, ssm0 = 0.f;
        float cmx1 = 0.f, csm1 = 0.f, smx1 = 0.f, ssm1 = 0.f;
        #pragma unroll 4
        for (int c = 0; c < CH; ++c) {
            unsigned pr = *(const unsigned*)(fb + (size_t)c * LL);
            float cmc = cms[c], mk = mks[c];
            float v0 = h2f((unsigned short)(pr & 0xFFFFu)) * cmc;
            float v1 = h2f((unsigned short)(pr >> 16)) * cmc;
            float vs0 = v0 * mk, vu0 = v0 - vs0;
            float vs1 = v1 * mk, vu1 = v1 - vs1;
            cmx0 = fmaxf(cmx0, vs0); smx0 = fmaxf(smx0, vu0); csm0 += vs0; ssm0 += vu0;
            cmx1 = fmaxf(cmx1, vs1); smx1 = fmaxf(smx1, vu1); csm1 += vs1; ssm1 += vu1;
        }
        int s0 = 3 + 2 * tid;
        st[0][s0] = cmx0;                  st[0][s0 + 1] = cmx1;
        st[1][s0] = csm0 * (1.0f / KCR);   st[1][s0 + 1] = csm1 * (1.0f / KCR);
        st[2][s0] = smx0;                  st[2][s0 + 1] = smx1;
        st[3][s0] = ssm0 * (1.0f / (CH - KCR));
        st[3][s0 + 1] = ssm1 * (1.0f / (CH - KCR));
    }
    // ---- halo stats: slots 0..2 and 515..517, one 32-lane group per slot ----
    if (tid < 192) {
        int slot = tid >> 5;                       // 0..5
        int w    = tid & 31;
        int sl   = (slot < 3) ? slot : 515 + (slot - 3);
        int l    = l0 - 3 + sl;
        float cmx = 0.f, csm = 0.f, smx = 0.f, ssm = 0.f;
        if (l >= 0 && l < LL) {
            const unsigned short* fb = f16 + (size_t)b * CH * LL + l;
            #pragma unroll
            for (int k = 0; k < 4; ++k) {
                int c = w + k * 32;
                float v  = h2f(fb[(size_t)c * LL]) * cms[c];
                float mk = mks[c];
                float vs = v * mk, vu = v - vs;
                cmx = fmaxf(cmx, vs); smx = fmaxf(smx, vu);
                csm += vs; ssm += vu;
            }
        }
        #pragma unroll
        for (int off = 1; off <= 16; off <<= 1) {
            csm += __shfl_xor(csm, off, 32);
            ssm += __shfl_xor(ssm, off, 32);
            cmx = fmaxf(cmx, __shfl_xor(cmx, off, 32));
            smx = fmaxf(smx, __shfl_xor(smx, off, 32));
        }
        if (w == 0) {
            st[0][sl] = cmx;
            st[1][sl] = csm * (1.0f / KCR);
            st[2][sl] = smx;
            st[3][sl] = ssm * (1.0f / (CH - KCR));
        }
    }
    __syncthreads();

    // ---- gate for both l's ----
    float inv = sabn_g[0] * rsqrtf(sabn_v[0] + EPSV);
    float bb2 = sabn_b[0] - sabn_m[0] * inv;
    float y1a = 0.f, y2a = 0.f, y1b = 0.f, y2b = 0.f;
    #pragma unroll
    for (int k = 0; k < 7; ++k) {
        float wm = sa_w[k], wa = sa_w[7 + k];
        int s0 = 2 * tid + k;
        y1a = fmaf(wm, st[0][s0],     fmaf(wa, st[1][s0],     y1a));
        y2a = fmaf(wm, st[2][s0],     fmaf(wa, st[3][s0],     y2a));
        y1b = fmaf(wm, st[0][s0 + 1], fmaf(wa, st[1][s0 + 1], y1b));
        y2b = fmaf(wm, st[2][s0 + 1], fmaf(wa, st[3][s0 + 1], y2b));
    }
    float A1a = 1.0f / (1.0f + expf(-fmaxf(y1a * inv + bb2, 0.f)));
    float A2a = 1.0f / (1.0f + expf(-fmaxf(y2a * inv + bb2, 0.f)));
    float A1b = 1.0f / (1.0f + expf(-fmaxf(y1b * inv + bb2, 0.f)));
    float A2b = 1.0f / (1.0f + expf(-fmaxf(y2b * inv + bb2, 0.f)));

    // ---- final: out = f*cm*(mask?A1:A2), float2 stores ----
    const unsigned short* fb = f16 + (size_t)b * CH * LL + l0 + 2 * tid;
    float* ob = out + (size_t)b * CH * LL + l0 + 2 * tid;
    #pragma unroll 4
    for (int c = 0; c < CH; ++c) {
        unsigned pr = *(const unsigned*)(fb + (size_t)c * LL);
        float cmc = cms[c];
        float v0 = h2f((unsigned short)(pr & 0xFFFFu)) * cmc;
        float v1 = h2f((unsigned short)(pr >> 16)) * cmc;
        bool sel = (mks[c] > 0.5f);
        float2 w;
        w.x = v0 * (sel ? A1a : A2a);
        w.y = v1 * (sel ? A1b : A2b);
        *(float2*)(ob + (size_t)c * LL) = w;
    }
}

extern "C" void kernel_launch(void* const* d_in, const int* in_sizes, int n_in,
                              void* d_out, int out_size, void* d_ws, size_t ws_size,
                              hipStream_t stream)
{
    const float* x      = (const float*)d_in[0];
    const float* conv_w = (const float*)d_in[1];
    const float* conv_b = (const float*)d_in[2];
    const float* bn_g   = (const float*)d_in[3];
    const float* bn_b   = (const float*)d_in[4];
    const float* bn_m   = (const float*)d_in[5];
    const float* bn_v   = (const float*)d_in[6];
    const float* alpha  = (const float*)d_in[7];
    const float* beta   = (const float*)d_in[8];
    const float* ca_w   = (const float*)d_in[9];
    const float* ca_b   = (const float*)d_in[10];
    const float* sa_w   = (const float*)d_in[11];
    const float* sabn_g = (const float*)d_in[12];
    const float* sabn_b = (const float*)d_in[13];
    const float* sabn_m = (const float*)d_in[14];
    const float* sabn_v = (const float*)d_in[15];

    float* out = (float*)d_out;
    float* ws  = (float*)d_ws;

    unsigned short* wpack = (unsigned short*)(ws + OFF_WPACK);
    float* bias2 = ws + OFF_BIAS2;
    float* psum  = ws + OFF_PSUM;
    float* pmax  = ws + OFF_PMAX;
    float* cmv_  = ws + OFF_CM;
    float* mskv  = ws + OFF_MASK;
    unsigned short* f16p = (unsigned short*)(ws + OFF_F16);

    prep_kernel<<<320, 256, 0, stream>>>(conv_w, conv_b, bn_g, bn_b, bn_m, bn_v,
                                         wpack, bias2);

    conv_mfma_kernel<<<dim3(BB, 128), 256, 0, stream>>>(x, wpack, bias2, f16p, psum, pmax);

    chan_kernel<<<BB, CH, 0, stream>>>(psum, pmax, alpha, beta, ca_w, ca_b, cmv_, mskv);

    sgf_kernel<<<dim3(32, BB), 256, 0, stream>>>(f16p, out, cmv_, mskv, sa_w,
                                                 sabn_g, sabn_b, sabn_m, sabn_v);
}

// Round 13
// 159.258 us; speedup vs baseline: 2.0348x; 1.0027x over previous
//
#include <hip/hip_runtime.h>
#include <hip/hip_bf16.h>
#include <math.h>

#define BB 16
#define IC 64
#define CH 128
#define LL 16384
#define KS 5
#define CAK 5
#define KCR 76
#define EPSV 1e-5f
#define NLT2 256          // psum/pmax partials per (b,c): 128 l-tiles x 2 half-waves

typedef short bf16x8 __attribute__((ext_vector_type(8)));
typedef float f32x16 __attribute__((ext_vector_type(16)));

// ---- workspace layout (in floats) ----
#define OFF_WPACK 0                          // 81920 ushort = 40960 floats (bf16 hi/lo A-frags)
#define OFF_BIAS2 40960                      // 128
#define OFF_PSUM  (OFF_BIAS2 + CH)           // 16*128*256
#define OFF_PMAX  (OFF_PSUM + BB*CH*NLT2)
#define OFF_CM    (OFF_PMAX + BB*CH*NLT2)    // 2048
#define OFF_MASK  (OFF_CM + BB*CH)
#define OFF_F16   (OFF_MASK + BB*CH)         // fp16 f: BB*CH*LL ushorts

__device__ __forceinline__ unsigned short f2bf(float f) {
    union { float f; unsigned u; } v; v.f = f;
    return (unsigned short)((v.u + 0x7FFFu + ((v.u >> 16) & 1u)) >> 16);
}
__device__ __forceinline__ float bf2f(unsigned short h) {
    union { unsigned u; float f; } v; v.u = ((unsigned)h) << 16;
    return v.f;
}
__device__ __forceinline__ unsigned short f2h(float f) {
    _Float16 h = (_Float16)f;
    return __builtin_bit_cast(unsigned short, h);
}
__device__ __forceinline__ float h2f(unsigned short u) {
    _Float16 h = __builtin_bit_cast(_Float16, u);
    return (float)h;
}

// DPP lane-shift (VALU pipe, no LDS). bound_ctrl=true: invalid lanes -> 0.
template<int CTRL>
__device__ __forceinline__ float dppf(float v) {
    return __builtin_bit_cast(float,
        __builtin_amdgcn_update_dpp(0, __builtin_bit_cast(int, v), CTRL, 0xF, 0xF, true));
}
__device__ __forceinline__ float dpp_sum32(float s) {
    s += dppf<0x111>(s);
    s += dppf<0x112>(s);
    s += dppf<0x114>(s);
    s += dppf<0x118>(s);
    s += dppf<0x142>(s);   // row_bcast:15 -> totals in lanes 31/63
    return s;
}
__device__ __forceinline__ float dpp_max32(float m) {
    m = fmaxf(m, dppf<0x111>(m));
    m = fmaxf(m, dppf<0x112>(m));
    m = fmaxf(m, dppf<0x114>(m));
    m = fmaxf(m, dppf<0x118>(m));
    m = fmaxf(m, dppf<0x142>(m));
    return m;
}

// ---------------------------------------------------------------------------
// Prep: fold BN scale into conv weights, split into bf16 hi/lo, pack in exact
// per-lane MFMA A-fragment order:
//   wpack[((((ver*2+ch2)*2+mt)*20+s)*64+ln)*8+j]
//     c = ch2*64 + mt*32 + (ln&31); kk = s>>2; i = (s&3)*16 + (ln>>5)*8 + j
// ---------------------------------------------------------------------------
__global__ void prep_kernel(const float* __restrict__ conv_w, const float* __restrict__ conv_b,
                            const float* __restrict__ bn_g, const float* __restrict__ bn_b,
                            const float* __restrict__ bn_m, const float* __restrict__ bn_v,
                            unsigned short* __restrict__ wpack, float* __restrict__ bias2)
{
    int e = blockIdx.x * 256 + threadIdx.x;
    if (e < 8 * 20 * 64 * 8) {
        int j    = e & 7;
        int ln   = (e >> 3) & 63;
        int rest = e >> 9;              // 0..159
        int s    = rest % 20;
        int mt   = (rest / 20) & 1;
        int ch2  = (rest / 40) & 1;
        int ver  = rest / 80;
        int c  = ch2 * 64 + mt * 32 + (ln & 31);
        int kk = s >> 2;
        int i  = (s & 3) * 16 + (ln >> 5) * 8 + j;
        float inv = bn_g[c] * rsqrtf(bn_v[c] + EPSV);
        float w = conv_w[(c * IC + i) * KS + kk] * inv;
        unsigned short h = f2bf(w);
        wpack[e] = (ver == 0) ? h : f2bf(w - bf2f(h));
    }
    if (e < CH) {
        float inv = bn_g[e] * rsqrtf(bn_v[e] + EPSV);
        bias2[e] = (conv_b[e] - bn_m[e]) * inv + bn_b[e];
    }
}

// ---------------------------------------------------------------------------
// Split-bf16 MFMA conv + BN + ReLU -> f (fp16, ws) + per-channel partial
// sum/max (DPP, fp32 pre-quant). Block = 128c x 128l, 4 waves of (64c x 64l).
// LDS tile xs[136][128] = [64 hi bf16 | 64 lo bf16], 16B chunks XOR-swizzled
// by (row&7). f = wh*xh + wh*xl + wl*xh  (fp32 MFMA accumulate, err ~4e-6).
// ---------------------------------------------------------------------------
__global__ __launch_bounds__(256, 4)
void conv_mfma_kernel(const float* __restrict__ x,
                      const unsigned short* __restrict__ wpack,
                      const float* __restrict__ bias2,
                      unsigned short* __restrict__ f16,
                      float* __restrict__ psum, float* __restrict__ pmax)
{
    __shared__ unsigned short xs[136 * 128];   // 34,816 B -> 4 blocks/CU
    const int b   = blockIdx.x;
    const int lt  = blockIdx.y;
    const int l0  = lt * 128;
    const int tid = threadIdx.x;
    const int ln  = tid & 63;
    const int wv  = __builtin_amdgcn_readfirstlane(tid >> 6);

    // ---- staging: wave wv owns i in [wv*16, wv*16+16); lane = row (l) ----
    const float* xb = x + (size_t)b * (IC * LL);
    const int ibase = wv * 16;
    #pragma unroll
    for (int g = 0; g < 3; ++g) {
        int row = g * 64 + ln;           // 0..191; valid rows < 136
        int l   = l0 - 4 + row;
        if (row < 136) {
            bool vl = (l >= 0) && (l < LL);
            float v[16];
            #pragma unroll
            for (int q = 0; q < 16; ++q)
                v[q] = vl ? xb[(size_t)(ibase + q) * LL + l] : 0.0f;
            int rs = row & 7;
            #pragma unroll
            for (int q2 = 0; q2 < 4; ++q2) {
                unsigned short h[4], lo[4];
                #pragma unroll
                for (int j = 0; j < 4; ++j) {
                    float vv = v[q2 * 4 + j];
                    h[j]  = f2bf(vv);
                    lo[j] = f2bf(vv - bf2f(h[j]));
                }
                int i0   = ibase + q2 * 4;
                int cc   = (i0 >> 3) ^ rs;
                int epos = row * 128 + cc * 8 + (i0 & 7);
                uint2 wh, wl;
                wh.x = (unsigned)h[0]  | ((unsigned)h[1]  << 16);
                wh.y = (unsigned)h[2]  | ((unsigned)h[3]  << 16);
                wl.x = (unsigned)lo[0] | ((unsigned)lo[1] << 16);
                wl.y = (unsigned)lo[2] | ((unsigned)lo[3] << 16);
                *(uint2*)&xs[epos]      = wh;
                *(uint2*)&xs[epos + 64] = wl;
            }
        }
    }
    __syncthreads();

    const int ch2  = wv >> 1;   // c-half: 0 -> c 0..63, 1 -> 64..127
    const int lh   = wv & 1;    // l-half within the 128-l tile
    const int ln31 = ln & 31;
    const int hi   = ln >> 5;
    const int rowbase = lh * 64 + ln31 + 2;

    // A-fragment stream pointers (wpack is L2-hot, 160 KB)
    const unsigned short* wp  = wpack + (size_t)ln * 8;
    const unsigned short* pA0 = wp + (size_t)((ch2 * 2 + 0) * 20) * 512;       // wh, mt0
    const unsigned short* pA1 = wp + (size_t)((ch2 * 2 + 1) * 20) * 512;       // wh, mt1
    const unsigned short* pA2 = wp + (size_t)(((2 + ch2) * 2 + 0) * 20) * 512; // wl, mt0
    const unsigned short* pA3 = wp + (size_t)(((2 + ch2) * 2 + 1) * 20) * 512; // wl, mt1

    f32x16 acc[2][2];
    #pragma unroll
    for (int mt = 0; mt < 2; ++mt)
        #pragma unroll
        for (int nt = 0; nt < 2; ++nt)
            #pragma unroll
            for (int r = 0; r < 16; ++r) acc[mt][nt][r] = 0.0f;

    auto loadA = [&](bf16x8* Av, int s) {
        Av[0] = *(const bf16x8*)(pA0 + (size_t)s * 512);
        Av[1] = *(const bf16x8*)(pA1 + (size_t)s * 512);
        Av[2] = *(const bf16x8*)(pA2 + (size_t)s * 512);
        Av[3] = *(const bf16x8*)(pA3 + (size_t)s * 512);
    };
    auto loadB = [&](bf16x8* Bv, int s) {
        int kk = s >> 2, iq = s & 3;
        int r0 = rowbase + kk;
        int r1 = r0 + 32;
        int c0 = ((iq << 1) + hi) ^ (r0 & 7);
        int c1 = ((iq << 1) + hi) ^ (r1 & 7);
        Bv[0] = *(const bf16x8*)&xs[r0 * 128 + c0 * 8];        // bh, nt0
        Bv[1] = *(const bf16x8*)&xs[r0 * 128 + 64 + c0 * 8];   // bl, nt0
        Bv[2] = *(const bf16x8*)&xs[r1 * 128 + c1 * 8];        // bh, nt1
        Bv[3] = *(const bf16x8*)&xs[r1 * 128 + 64 + c1 * 8];   // bl, nt1
    };
    // Interleaved across the 4 accumulators: same-acc dep distance = 4.
    auto compute = [&](const bf16x8* Av, const bf16x8* Bv) {
        acc[0][0] = __builtin_amdgcn_mfma_f32_32x32x16_bf16(Av[0], Bv[0], acc[0][0], 0, 0, 0);
        acc[1][0] = __builtin_amdgcn_mfma_f32_32x32x16_bf16(Av[1], Bv[0], acc[1][0], 0, 0, 0);
        acc[0][1] = __builtin_amdgcn_mfma_f32_32x32x16_bf16(Av[0], Bv[2], acc[0][1], 0, 0, 0);
        acc[1][1] = __builtin_amdgcn_mfma_f32_32x32x16_bf16(Av[1], Bv[2], acc[1][1], 0, 0, 0);
        acc[0][0] = __builtin_amdgcn_mfma_f32_32x32x16_bf16(Av[0], Bv[1], acc[0][0], 0, 0, 0);
        acc[1][0] = __builtin_amdgcn_mfma_f32_32x32x16_bf16(Av[1], Bv[1], acc[1][0], 0, 0, 0);
        acc[0][1] = __builtin_amdgcn_mfma_f32_32x32x16_bf16(Av[0], Bv[3], acc[0][1], 0, 0, 0);
        acc[1][1] = __builtin_amdgcn_mfma_f32_32x32x16_bf16(Av[1], Bv[3], acc[1][1], 0, 0, 0);
        acc[0][0] = __builtin_amdgcn_mfma_f32_32x32x16_bf16(Av[2], Bv[0], acc[0][0], 0, 0, 0);
        acc[1][0] = __builtin_amdgcn_mfma_f32_32x32x16_bf16(Av[3], Bv[0], acc[1][0], 0, 0, 0);
        acc[0][1] = __builtin_amdgcn_mfma_f32_32x32x16_bf16(Av[2], Bv[2], acc[0][1], 0, 0, 0);
        acc[1][1] = __builtin_amdgcn_mfma_f32_32x32x16_bf16(Av[3], Bv[2], acc[1][1], 0, 0, 0);
    };

    // ---- main loop: 3-deep A ring, 2-deep B ring ----
    bf16x8 Ar[3][4], Br[2][4];
    loadA(Ar[0], 0); loadA(Ar[1], 1); loadA(Ar[2], 2);
    loadB(Br[0], 0); loadB(Br[1], 1);
    #pragma unroll
    for (int s = 0; s < 20; ++s) {
        compute(Ar[s % 3], Br[s & 1]);
        if (s + 3 < 20) loadA(Ar[s % 3], s + 3);
        if (s + 2 < 20) loadB(Br[s & 1], s + 2);
    }

    // ---- epilogue: bias + relu, store f16, per-channel partial sum/max ----
    // D mapping (32x32): col(l)=ln&31, row(c)=(r&3)+8*(r>>2)+4*(ln>>5)
    const int lgbase = l0 + lh * 64 + ln31;
    #pragma unroll
    for (int mt = 0; mt < 2; ++mt) {
        #pragma unroll
        for (int nt = 0; nt < 2; ++nt) {
            #pragma unroll
            for (int r = 0; r < 16; ++r) {
                int c = ch2 * 64 + mt * 32 + (r & 3) + 8 * (r >> 2) + 4 * hi;
                float fv = fmaxf(acc[mt][nt][r] + bias2[c], 0.0f);
                f16[((size_t)(b * CH + c)) * LL + lgbase + nt * 32] = f2h(fv);
                acc[mt][nt][r] = fv;
            }
        }
    }
    // per-channel partial sum/max over this wave's 64 l's, via DPP (no LDS).
    #pragma unroll
    for (int mt = 0; mt < 2; ++mt) {
        #pragma unroll
        for (int r = 0; r < 16; ++r) {
            float s = dpp_sum32(acc[mt][0][r] + acc[mt][1][r]);
            float m = dpp_max32(fmaxf(acc[mt][0][r], acc[mt][1][r]));
            if (ln31 == 31) {
                int c   = ch2 * 64 + mt * 32 + (r & 3) + 8 * (r >> 2) + 4 * hi;
                int lt2 = lt * 2 + lh;
                psum[(b * CH + c) * NLT2 + lt2] = s;
                pmax[(b * CH + c) * NLT2 + lt2] = m;
            }
        }
    }
}

// ---------------------------------------------------------------------------
// Per-batch: finish L-reductions (float4-vectorized), channel attention,
// top-K mask (rank count, ties by lower index = jax.lax.top_k). Grid: B x 128.
// ---------------------------------------------------------------------------
__global__ void chan_kernel(const float* __restrict__ psum, const float* __restrict__ pmax,
                            const float* __restrict__ alpha, const float* __restrict__ beta,
                            const float* __restrict__ ca_w, const float* __restrict__ ca_b,
                            float* __restrict__ cm, float* __restrict__ maskv)
{
    int b = blockIdx.x;
    int c = threadIdx.x;   // 128
    const float4* ps4 = (const float4*)(psum + (size_t)(b * CH + c) * NLT2);
    const float4* pm4 = (const float4*)(pmax + (size_t)(b * CH + c) * NLT2);
    float s = 0.0f, m = 0.0f;
    #pragma unroll 4
    for (int t = 0; t < NLT2 / 4; ++t) {
        float4 a = ps4[t];
        float4 q = pm4[t];
        s += (a.x + a.y) + (a.z + a.w);
        m = fmaxf(m, fmaxf(fmaxf(q.x, q.y), fmaxf(q.z, q.w)));
    }
    float favg = s * (1.0f / LL);
    float fadd = (alpha[0] + 0.5f) * favg + (beta[0] + 0.5f) * m;

    __shared__ float fa[CH];
    __shared__ float cms[CH];
    fa[c] = fadd;
    __syncthreads();

    float z = ca_b[0];
    #pragma unroll
    for (int k = 0; k < CAK; ++k) {
        int cc = c + k - 2;
        float v = (cc >= 0 && cc < CH) ? fa[cc] : 0.0f;
        z = fmaf(ca_w[k], v, z);
    }
    float cmv = 1.0f / (1.0f + expf(-z));
    cms[c] = cmv;
    __syncthreads();

    int rank = 0;
    for (int cc = 0; cc < CH; ++cc) {
        float o = cms[cc];
        rank += (o > cmv || (o == cmv && cc < c)) ? 1 : 0;
    }
    cm[b * CH + c] = cmv;
    maskv[b * CH + c] = (rank < KCR) ? 1.0f : 0.0f;
}

// ---------------------------------------------------------------------------
// Fused stats + gate + final. ONE l per thread, 256-l tiles, grid 64x16 =
// 1024 blocks -> 4 blocks/CU (16 waves/CU) for latency hiding (was 512 blocks
// = 8 waves/CU). A wave's 64 ushort loads still cover a full 128B line and
// adjacent waves share 256B lines, so line-level traffic is unchanged.
// Halo stat slots via 6 x 32-lane groups.
// ---------------------------------------------------------------------------
__global__ __launch_bounds__(256)
void sgf_kernel(const unsigned short* __restrict__ f16, float* __restrict__ out,
                const float* __restrict__ cm, const float* __restrict__ maskv,
                const float* __restrict__ sa_w,
                const float* __restrict__ sabn_g, const float* __restrict__ sabn_b,
                const float* __restrict__ sabn_m, const float* __restrict__ sabn_v)
{
    __shared__ float cms[CH], mks[CH];
    __shared__ float st[4][264];                  // 262 used: 3 + 256 + 3
    const int g   = blockIdx.x;    // 0..63 (256-l tile)
    const int b   = blockIdx.y;
    const int l0  = g * 256;
    const int tid = threadIdx.x;
    if (tid < CH) { cms[tid] = cm[b * CH + tid]; mks[tid] = maskv[b * CH + tid]; }
    __syncthreads();

    // ---- interior stats: one l per thread ----
    {
        const unsigned short* fb = f16 + (size_t)b * CH * LL + l0 + tid;
        float cmx = 0.f, csm = 0.f, smx = 0.f, ssm = 0.f;
        #pragma unroll 4
        for (int c = 0; c < CH; ++c) {
            float v  = h2f(fb[(size_t)c * LL]) * cms[c];
            float mk = mks[c];
            float vs = v * mk, vu = v - vs;
            cmx = fmaxf(cmx, vs);
            smx = fmaxf(smx, vu);
            csm += vs;
            ssm += vu;
        }
        st[0][3 + tid] = cmx;
        st[1][3 + tid] = csm * (1.0f / KCR);
        st[2][3 + tid] = smx;
        st[3][3 + tid] = ssm * (1.0f / (CH - KCR));
    }
    // ---- halo stats: slots 0..2 and 259..261, one 32-lane group per slot ----
    if (tid < 192) {
        int slot = tid >> 5;                       // 0..5
        int w    = tid & 31;
        int sl   = (slot < 3) ? slot : 259 + (slot - 3);
        int l    = l0 - 3 + sl;
        float cmx = 0.f, csm = 0.f, smx = 0.f, ssm = 0.f;
        if (l >= 0 && l < LL) {
            const unsigned short* fb = f16 + (size_t)b * CH * LL + l;
            #pragma unroll
            for (int k = 0; k < 4; ++k) {
                int c = w + k * 32;
                float v  = h2f(fb[(size_t)c * LL]) * cms[c];
                float mk = mks[c];
                float vs = v * mk, vu = v - vs;
                cmx = fmaxf(cmx, vs); smx = fmaxf(smx, vu);
                csm += vs; ssm += vu;
            }
        }
        #pragma unroll
        for (int off = 1; off <= 16; off <<= 1) {
            csm += __shfl_xor(csm, off, 32);
            ssm += __shfl_xor(ssm, off, 32);
            cmx = fmaxf(cmx, __shfl_xor(cmx, off, 32));
            smx = fmaxf(smx, __shfl_xor(smx, off, 32));
        }
        if (w == 0) {
            st[0][sl] = cmx;
            st[1][sl] = csm * (1.0f / KCR);
            st[2][sl] = smx;
            st[3][sl] = ssm * (1.0f / (CH - KCR));
        }
    }
    __syncthreads();

    // ---- gate for this thread's l ----
    float inv = sabn_g[0] * rsqrtf(sabn_v[0] + EPSV);
    float bb2 = sabn_b[0] - sabn_m[0] * inv;
    float y1 = 0.f, y2 = 0.f;
    #pragma unroll
    for (int k = 0; k < 7; ++k) {
        float wm = sa_w[k], wa = sa_w[7 + k];
        y1 = fmaf(wm, st[0][tid + k], fmaf(wa, st[1][tid + k], y1));
        y2 = fmaf(wm, st[2][tid + k], fmaf(wa, st[3][tid + k], y2));
    }
    float A1 = 1.0f / (1.0f + expf(-fmaxf(y1 * inv + bb2, 0.f)));
    float A2 = 1.0f / (1.0f + expf(-fmaxf(y2 * inv + bb2, 0.f)));

    // ---- final: out = f*cm*(mask?A1:A2) ----
    const unsigned short* fb = f16 + (size_t)b * CH * LL + l0 + tid;
    float* ob = out + (size_t)b * CH * LL + l0 + tid;
    #pragma unroll 4
    for (int c = 0; c < CH; ++c) {
        float v = h2f(fb[(size_t)c * LL]) * cms[c];
        float a = (mks[c] > 0.5f) ? A1 : A2;
        ob[(size_t)c * LL] = v * a;
    }
}

extern "C" void kernel_launch(void* const* d_in, const int* in_sizes, int n_in,
                              void* d_out, int out_size, void* d_ws, size_t ws_size,
                              hipStream_t stream)
{
    const float* x      = (const float*)d_in[0];
    const float* conv_w = (const float*)d_in[1];
    const float* conv_b = (const float*)d_in[2];
    const float* bn_g   = (const float*)d_in[3];
    const float* bn_b   = (const float*)d_in[4];
    const float* bn_m   = (const float*)d_in[5];
    const float* bn_v   = (const float*)d_in[6];
    const float* alpha  = (const float*)d_in[7];
    const float* beta   = (const float*)d_in[8];
    const float* ca_w   = (const float*)d_in[9];
    const float* ca_b   = (const float*)d_in[10];
    const float* sa_w   = (const float*)d_in[11];
    const float* sabn_g = (const float*)d_in[12];
    const float* sabn_b = (const float*)d_in[13];
    const float* sabn_m = (const float*)d_in[14];
    const float* sabn_v = (const float*)d_in[15];

    float* out = (float*)d_out;
    float* ws  = (float*)d_ws;

    unsigned short* wpack = (unsigned short*)(ws + OFF_WPACK);
    float* bias2 = ws + OFF_BIAS2;
    float* psum  = ws + OFF_PSUM;
    float* pmax  = ws + OFF_PMAX;
    float* cmv_  = ws + OFF_CM;
    float* mskv  = ws + OFF_MASK;
    unsigned short* f16p = (unsigned short*)(ws + OFF_F16);

    prep_kernel<<<320, 256, 0, stream>>>(conv_w, conv_b, bn_g, bn_b, bn_m, bn_v,
                                         wpack, bias2);

    conv_mfma_kernel<<<dim3(BB, 128), 256, 0, stream>>>(x, wpack, bias2, f16p, psum, pmax);

    chan_kernel<<<BB, CH, 0, stream>>>(psum, pmax, alpha, beta, ca_w, ca_b, cmv_, mskv);

    sgf_kernel<<<dim3(64, BB), 256, 0, stream>>>(f16p, out, cmv_, mskv, sa_w,
                                                 sabn_g, sabn_b, sabn_m, sabn_v);
}